// Round 24
// baseline (117.342 us; speedup 1.0000x reference)
//
#include <hip/hip_runtime.h>
#include <hip/hip_fp8.h>

#define D 256
#define SCALE 1.69864354f   // sqrt((1/T)*log2e), T=0.5: acc=2.8854*cos -> exp2(acc)=exp(sim/T)
#define EPS 1e-8f

typedef __attribute__((ext_vector_type(4))) float f32x4;
typedef long fp8x8;   // 8 packed e4m3 bytes = one MFMA A/B fragment register pair

// ------ Kernel A: row-normalize [z1;z2] -> fp8 fn (pre-scaled), fused pos ---
// Also zeroes syncarr[0..64] (rowcnt[64] + done2) each call.
__global__ __launch_bounds__(256) void normpos_kernel(
    const float* __restrict__ z1, const float* __restrict__ z2,
    unsigned char* __restrict__ fnq, float* __restrict__ pos,
    int* __restrict__ syncarr, int N) {
  if (blockIdx.x == 0 && threadIdx.x < 65) syncarr[threadIdx.x] = 0;
  int wid  = threadIdx.x >> 6;
  int lane = threadIdx.x & 63;
  int row  = blockIdx.x * 4 + wid;
  f32x4 a = *(const f32x4*)(z1 + (size_t)row * D + lane * 4);
  f32x4 b = *(const f32x4*)(z2 + (size_t)row * D + lane * 4);
  float s1  = a.x * a.x + a.y * a.y + a.z * a.z + a.w * a.w;
  float s2  = b.x * b.x + b.y * b.y + b.z * b.z + b.w * b.w;
  float dot = a.x * b.x + a.y * b.y + a.z * b.z + a.w * b.w;
  #pragma unroll
  for (int m = 1; m < 64; m <<= 1) {
    s1  += __shfl_xor(s1, m, 64);
    s2  += __shfl_xor(s2, m, 64);
    dot += __shfl_xor(dot, m, 64);
  }
  float inv1 = 1.0f / fmaxf(sqrtf(s1), EPS);
  float inv2 = 1.0f / fmaxf(sqrtf(s2), EPS);
  float q1 = inv1 * SCALE, q2 = inv2 * SCALE;
  unsigned int w1 = 0, w2 = 0;
  #pragma unroll
  for (int j = 0; j < 4; ++j) {
    w1 |= (unsigned int)__hip_cvt_float_to_fp8(a[j] * q1, __HIP_SATFINITE,
                                               __HIP_E4M3) << (8 * j);
    w2 |= (unsigned int)__hip_cvt_float_to_fp8(b[j] * q2, __HIP_SATFINITE,
                                               __HIP_E4M3) << (8 * j);
  }
  *(unsigned int*)(fnq + (size_t)row * D + lane * 4)       = w1;
  *(unsigned int*)(fnq + (size_t)(N + row) * D + lane * 4) = w2;
  if (lane == 0) pos[row] = dot * inv1 * inv2;
}

// -------- Kernel B: denom + distributed reduction, fp8 triangle GEMM -------
// Hot loop/tile/swizzle BYTE-IDENTICAL to R13 (52.8us best): 128x128 tile,
// 4 waves, single-buffered, BK=128 (2 kk x 4 ks), launch_bounds(256,4),
// 34 KB LDS -> 4 blocks/CU. New: NO reduce kernel. After partial writes,
// each tile releases (syncthreads + threadfence + atomicAdd rowcnt[rb], and
// rowcnt[cb] if off-diag). The 64th arriver for row-block R reduces R's
// 128 rows x 64 splits -> bsum2[R]; the 64th bsum2 finisher computes the
// scalar loss. Fixed summation orders -> bit-deterministic.
// mfma_f32_16x16x32_fp8_fp8: A/B row/col=lane&15, k-byte=(lane>>4)*8+j;
// C/D col=lane&15, row=(lane>>4)*4+reg (dtype-independent, m121-m128).

__device__ __forceinline__ void stage_tile(const unsigned char* __restrict__ row0,
                                           int kk, unsigned char* lds, int tid) {
  // 128 rows x 128 k fp8 (16 KB) = 1024 chunks of 16B; 4 iters x 256 thr.
  #pragma unroll
  for (int it = 0; it < 4; ++it) {
    int s = it * 256 + tid;        // chunk slot; per-wave base + lane*16B ✓
    int r = s >> 3;                // row in tile
    int p = s & 7;                 // chunk-in-row (LDS position)
    const unsigned char* src =
        row0 + (size_t)r * D + kk * 128 + ((p ^ (r & 7)) << 4);
    __builtin_amdgcn_global_load_lds(
        (const __attribute__((address_space(1))) void*)src,
        (__attribute__((address_space(3))) void*)(lds + s * 16), 16, 0, 0);
  }
}

__global__ __launch_bounds__(256, 4) void denom_kernel(
    const unsigned char* __restrict__ fnq, float* __restrict__ partial,
    const float* __restrict__ pos, float* __restrict__ bsum2,
    int* __restrict__ syncarr, float* __restrict__ out, int twoN, int N) {
  __shared__ unsigned char As[128 * 128];   // 16 KB
  __shared__ unsigned char Bs[128 * 128];   // 16 KB
  __shared__ float redR[128][2];            // 1 KB
  __shared__ float redC[128][2];            // 1 KB
  __shared__ float sred[4];
  __shared__ int finA, finB, sfinal;

  int tid  = threadIdx.x;
  int wid  = tid >> 6;
  int lane = tid & 63;
  int c = lane & 15;            // frag row/col within 16-tile
  int g = lane >> 4;            // k-group (in) / row-group (out)
  int wr = wid >> 1, wc = wid & 1;

  // decode lower-triangle linear index -> (rb<=cb)
  int bid = blockIdx.x;
  int i = (int)((sqrtf(8.f * (float)bid + 1.f) - 1.f) * 0.5f);
  while ((i + 1) * (i + 2) / 2 <= bid) ++i;
  while (i * (i + 1) / 2 > bid) --i;
  int rb = bid - i * (i + 1) / 2;   // row block  (rb <= cb)
  int cb = i;                       // col block
  const unsigned char* Arow0 = fnq + (size_t)rb * 128 * D;
  const unsigned char* Brow0 = fnq + (size_t)cb * 128 * D;

  bool dblk  = (rb == cb);
  bool dwave = dblk && (wr == wc);

  f32x4 acc[4][4] = {};

  stage_tile(Arow0, 0, As, tid);
  stage_tile(Brow0, 0, Bs, tid);

  #pragma unroll
  for (int kk = 0; kk < 2; ++kk) {
    __syncthreads();   // stage complete (vmcnt drained before barrier)
    #pragma unroll
    for (int ks = 0; ks < 4; ++ks) {
      fp8x8 a[4], b[4];
      int q  = (ks << 1) | (g >> 1);   // 16B-chunk index of this k-group
      int h  = (g & 1) << 3;           // 8B half within chunk
      #pragma unroll
      for (int mi = 0; mi < 4; ++mi) {
        int ar = wr * 64 + mi * 16 + c;
        a[mi] = *(const fp8x8*)(As + ar * 128 + ((q ^ (ar & 7)) << 4) + h);
      }
      #pragma unroll
      for (int ni = 0; ni < 4; ++ni) {
        int bc = wc * 64 + ni * 16 + c;
        b[ni] = *(const fp8x8*)(Bs + bc * 128 + ((q ^ (bc & 7)) << 4) + h);
      }
      #pragma unroll
      for (int mi = 0; mi < 4; ++mi)
        #pragma unroll
        for (int ni = 0; ni < 4; ++ni)
          acc[mi][ni] = __builtin_amdgcn_mfma_f32_16x16x32_fp8_fp8(
              a[mi], b[ni], acc[mi][ni], 0, 0, 0);
    }
    if (kk == 0) {
      __syncthreads();               // protect LDS before restage
      stage_tile(Arow0, 1, As, tid);
      stage_tile(Brow0, 1, Bs, tid);
    }
  }

  // ---- epilogue: e = exp2(acc) (scale pre-folded); 3 wave-uniform paths ----
  float rsum[16];
  float csum[4];
  #pragma unroll
  for (int ii = 0; ii < 16; ++ii) rsum[ii] = 0.f;
  #pragma unroll
  for (int ii = 0; ii < 4; ++ii) csum[ii] = 0.f;

  if (dwave) {
    #pragma unroll
    for (int mi = 0; mi < 4; ++mi)
      #pragma unroll
      for (int ni = 0; ni < 4; ++ni) {
        int colloc = ni * 16 + c;
        #pragma unroll
        for (int r = 0; r < 4; ++r) {
          int rowloc = mi * 16 + g * 4 + r;
          float e = __builtin_amdgcn_exp2f(acc[mi][ni][r]);
          if (rowloc == colloc) e = 0.f;
          rsum[mi * 4 + r] += e;
        }
      }
  } else if (dblk) {
    #pragma unroll
    for (int mi = 0; mi < 4; ++mi)
      #pragma unroll
      for (int ni = 0; ni < 4; ++ni)
        #pragma unroll
        for (int r = 0; r < 4; ++r)
          rsum[mi * 4 + r] += __builtin_amdgcn_exp2f(acc[mi][ni][r]);
  } else {
    #pragma unroll
    for (int mi = 0; mi < 4; ++mi)
      #pragma unroll
      for (int ni = 0; ni < 4; ++ni)
        #pragma unroll
        for (int r = 0; r < 4; ++r) {
          float e = __builtin_amdgcn_exp2f(acc[mi][ni][r]);
          rsum[mi * 4 + r] += e;
          csum[ni]         += e;
        }
  }

  // row sums: reduce across the 16 column-lanes (lane bits 0-3)
  #pragma unroll
  for (int ii = 0; ii < 16; ++ii) {
    float v = rsum[ii];
    v += __shfl_xor(v, 1, 64);
    v += __shfl_xor(v, 2, 64);
    v += __shfl_xor(v, 4, 64);
    v += __shfl_xor(v, 8, 64);
    rsum[ii] = v;
  }
  if (c == 0) {
    #pragma unroll
    for (int mi = 0; mi < 4; ++mi)
      #pragma unroll
      for (int r = 0; r < 4; ++r)
        redR[wr * 64 + mi * 16 + g * 4 + r][wc] = rsum[mi * 4 + r];
  }
  if (!dblk) {
    #pragma unroll
    for (int ii = 0; ii < 4; ++ii) {
      float v = csum[ii];
      v += __shfl_xor(v, 16, 64);
      v += __shfl_xor(v, 32, 64);
      csum[ii] = v;
    }
    if (g == 0) {
      #pragma unroll
      for (int ni = 0; ni < 4; ++ni)
        redC[wc * 64 + ni * 16 + c][wr] = csum[ni];
    }
  }
  __syncthreads();
  if (tid < 128) {
    partial[(size_t)cb * twoN + rb * 128 + tid] =
        redR[tid][0] + redR[tid][1];
    if (rb != cb)
      partial[(size_t)rb * twoN + cb * 128 + tid] =
          redC[tid][0] + redC[tid][1];
  }

  // ---- release: stores drained by syncthreads; tid0 fences + arrives ----
  __syncthreads();
  if (tid == 0) {
    __threadfence();
    finA = atomicAdd(&syncarr[rb], 1);
    finB = dblk ? -1 : atomicAdd(&syncarr[cb], 1);
  }
  __syncthreads();

  // ---- finisher chain: 64th arriver of row-block R reduces it ----
  #pragma unroll
  for (int w = 0; w < 2; ++w) {
    int R   = w ? cb : rb;
    int arr = w ? finB : finA;
    if (arr != 63) continue;       // block-uniform
    __threadfence();               // acquire: see all 64 contributors
    int row  = tid >> 1;           // 0..127
    int half = tid & 1;
    float dsum = 0.f;
    for (int s = half * 32; s < half * 32 + 32; ++s)
      dsum += partial[(size_t)s * twoN + R * 128 + row];
    dsum += __shfl_xor(dsum, 1, 64);          // combine the two halves
    float lg = (half == 0) ? logf(dsum) : 0.f;
    float v = lg;
    #pragma unroll
    for (int m = 2; m < 64; m <<= 1) v += __shfl_xor(v, m, 64);
    if (lane == 0) sred[wid] = v;
    __syncthreads();
    if (tid == 0) {
      bsum2[R] = sred[0] + sred[1] + sred[2] + sred[3];
      __threadfence();
      sfinal = (atomicAdd(&syncarr[64], 1) == 63);
    }
    __syncthreads();
    if (sfinal) {
      __threadfence();             // acquire all bsum2
      float ls = (tid < 64) ? bsum2[tid] : 0.f;
      float ps = 0.f;
      for (int k = tid; k < N; k += 256) ps += pos[k];
      #pragma unroll
      for (int m = 1; m < 64; m <<= 1) {
        ls += __shfl_xor(ls, m, 64);
        ps += __shfl_xor(ps, m, 64);
      }
      __shared__ float sl[4], sp[4];
      if (lane == 0) { sl[wid] = ls; sp[wid] = ps; }
      __syncthreads();
      if (tid == 0)
        out[0] = (sl[0] + sl[1] + sl[2] + sl[3]) / (float)twoN -
                 2.f * (sp[0] + sp[1] + sp[2] + sp[3]) / (float)N;
    }
  }
}

extern "C" void kernel_launch(void* const* d_in, const int* in_sizes, int n_in,
                              void* d_out, int out_size, void* d_ws,
                              size_t ws_size, hipStream_t stream) {
  const float* z1 = (const float*)d_in[0];
  const float* z2 = (const float*)d_in[1];
  int N = in_sizes[0] / D;   // 4096
  int twoN = 2 * N;          // 8192
  int nrb = twoN / 128;      // 64

  // workspace layout
  unsigned char* fnq = (unsigned char*)d_ws;                     // 2 MB fp8
  float* partial = (float*)((char*)d_ws + (size_t)twoN * D);     // 2 MB
  float* pos     = (float*)((char*)partial + (size_t)nrb * twoN * 4);
  float* bsum2   = (float*)((char*)pos + (size_t)N * 4);         // 64 floats
  int*   syncarr = (int*)((char*)bsum2 + 256 * 4);               // 65 ints

  normpos_kernel<<<N / 4, 256, 0, stream>>>(z1, z2, fnq, pos, syncarr, N);
  int ntri = nrb * (nrb + 1) / 2;  // 2080 upper-triangle blocks
  denom_kernel<<<ntri, 256, 0, stream>>>(fnq, partial, pos, bsum2, syncarr,
                                         (float*)d_out, twoN, N);
}

// Round 25
// 52.703 us; speedup vs baseline: 2.2265x; 2.2265x over previous
//
#include <hip/hip_runtime.h>
#include <hip/hip_fp8.h>

#define D 256
#define SCALE 1.69864354f   // sqrt((1/T)*log2e), T=0.5: acc=2.8854*cos -> exp2(acc)=exp(sim/T)
#define EPS 1e-8f

typedef __attribute__((ext_vector_type(4))) float f32x4;
typedef long fp8x8;   // 8 packed e4m3 bytes = one MFMA A/B fragment register pair

// ------ Kernel A: row-normalize [z1;z2] -> fp8 fn (pre-scaled), fused pos ---
// Also zeroes the reduce sync counter (runs before reduce in stream order).
__global__ __launch_bounds__(256) void normpos_kernel(
    const float* __restrict__ z1, const float* __restrict__ z2,
    unsigned char* __restrict__ fnq, float* __restrict__ pos,
    int* __restrict__ sync, int N) {
  if (blockIdx.x == 0 && threadIdx.x == 0) *sync = 0;
  int wid  = threadIdx.x >> 6;
  int lane = threadIdx.x & 63;
  int row  = blockIdx.x * 4 + wid;
  f32x4 a = *(const f32x4*)(z1 + (size_t)row * D + lane * 4);
  f32x4 b = *(const f32x4*)(z2 + (size_t)row * D + lane * 4);
  float s1  = a.x * a.x + a.y * a.y + a.z * a.z + a.w * a.w;
  float s2  = b.x * b.x + b.y * b.y + b.z * b.z + b.w * b.w;
  float dot = a.x * b.x + a.y * b.y + a.z * b.z + a.w * b.w;
  #pragma unroll
  for (int m = 1; m < 64; m <<= 1) {
    s1  += __shfl_xor(s1, m, 64);
    s2  += __shfl_xor(s2, m, 64);
    dot += __shfl_xor(dot, m, 64);
  }
  float inv1 = 1.0f / fmaxf(sqrtf(s1), EPS);
  float inv2 = 1.0f / fmaxf(sqrtf(s2), EPS);
  float q1 = inv1 * SCALE, q2 = inv2 * SCALE;
  unsigned int w1 = 0, w2 = 0;
  #pragma unroll
  for (int j = 0; j < 4; ++j) {
    w1 |= (unsigned int)__hip_cvt_float_to_fp8(a[j] * q1, __HIP_SATFINITE,
                                               __HIP_E4M3) << (8 * j);
    w2 |= (unsigned int)__hip_cvt_float_to_fp8(b[j] * q2, __HIP_SATFINITE,
                                               __HIP_E4M3) << (8 * j);
  }
  *(unsigned int*)(fnq + (size_t)row * D + lane * 4)       = w1;
  *(unsigned int*)(fnq + (size_t)(N + row) * D + lane * 4) = w2;
  if (lane == 0) pos[row] = dot * inv1 * inv2;
}

// -------- Kernel B: denom partials, fp8 symmetric upper-triangle GEMM ------
// R13 proven optimum (52.8us): 128x128 tile, 4 waves, single-buffered,
// BK=128 (2 kk x 4 ks, 64 MFMA per barrier-pair), launch_bounds(256,4),
// 34 KB LDS -> 4 blocks/CU. Triangle rb<=cb; rowsum -> partial[cb][rb-rows],
// colsum -> partial[rb][cb-rows] (off-diag). Reduce buffers alias As/Bs
// after a post-MFMA barrier. Chunk swizzle: inverse-swizzled GLOBAL source +
// swizzled ds_read, linear LDS dest (rule #21).
// mfma_f32_16x16x32_fp8_fp8: A/B row/col=lane&15, k-byte=(lane>>4)*8+j;
// C/D col=lane&15, row=(lane>>4)*4+reg (dtype-independent, m121-m128).

__device__ __forceinline__ void stage_tile(const unsigned char* __restrict__ row0,
                                           int kk, unsigned char* lds, int tid) {
  // 128 rows x 128 k fp8 (16 KB) = 1024 chunks of 16B; 4 iters x 256 thr.
  #pragma unroll
  for (int it = 0; it < 4; ++it) {
    int s = it * 256 + tid;        // chunk slot; per-wave base + lane*16B ✓
    int r = s >> 3;                // row in tile
    int p = s & 7;                 // chunk-in-row (LDS position)
    const unsigned char* src =
        row0 + (size_t)r * D + kk * 128 + ((p ^ (r & 7)) << 4);
    __builtin_amdgcn_global_load_lds(
        (const __attribute__((address_space(1))) void*)src,
        (__attribute__((address_space(3))) void*)(lds + s * 16), 16, 0, 0);
  }
}

__global__ __launch_bounds__(256, 4) void denom_kernel(
    const unsigned char* __restrict__ fnq, float* __restrict__ partial,
    int twoN) {
  __shared__ unsigned char As[128 * 128];   // 16 KB
  __shared__ unsigned char Bs[128 * 128];   // 16 KB
  __shared__ float redR[128][2];            // 1 KB
  __shared__ float redC[128][2];            // 1 KB

  int tid  = threadIdx.x;
  int wid  = tid >> 6;
  int lane = tid & 63;
  int c = lane & 15;            // frag row/col within 16-tile
  int g = lane >> 4;            // k-group (in) / row-group (out)
  int wr = wid >> 1, wc = wid & 1;

  // decode lower-triangle linear index -> (rb<=cb)
  int bid = blockIdx.x;
  int i = (int)((sqrtf(8.f * (float)bid + 1.f) - 1.f) * 0.5f);
  while ((i + 1) * (i + 2) / 2 <= bid) ++i;
  while (i * (i + 1) / 2 > bid) --i;
  int rb = bid - i * (i + 1) / 2;   // row block  (rb <= cb)
  int cb = i;                       // col block
  const unsigned char* Arow0 = fnq + (size_t)rb * 128 * D;
  const unsigned char* Brow0 = fnq + (size_t)cb * 128 * D;

  bool dblk  = (rb == cb);
  bool dwave = dblk && (wr == wc);

  f32x4 acc[4][4] = {};

  stage_tile(Arow0, 0, As, tid);
  stage_tile(Brow0, 0, Bs, tid);

  #pragma unroll
  for (int kk = 0; kk < 2; ++kk) {
    __syncthreads();   // stage complete (vmcnt drained before barrier)
    #pragma unroll
    for (int ks = 0; ks < 4; ++ks) {
      fp8x8 a[4], b[4];
      int q  = (ks << 1) | (g >> 1);   // 16B-chunk index of this k-group
      int h  = (g & 1) << 3;           // 8B half within chunk
      #pragma unroll
      for (int mi = 0; mi < 4; ++mi) {
        int ar = wr * 64 + mi * 16 + c;
        a[mi] = *(const fp8x8*)(As + ar * 128 + ((q ^ (ar & 7)) << 4) + h);
      }
      #pragma unroll
      for (int ni = 0; ni < 4; ++ni) {
        int bc = wc * 64 + ni * 16 + c;
        b[ni] = *(const fp8x8*)(Bs + bc * 128 + ((q ^ (bc & 7)) << 4) + h);
      }
      #pragma unroll
      for (int mi = 0; mi < 4; ++mi)
        #pragma unroll
        for (int ni = 0; ni < 4; ++ni)
          acc[mi][ni] = __builtin_amdgcn_mfma_f32_16x16x32_fp8_fp8(
              a[mi], b[ni], acc[mi][ni], 0, 0, 0);
    }
    if (kk == 0) {
      __syncthreads();               // protect LDS before restage
      stage_tile(Arow0, 1, As, tid);
      stage_tile(Brow0, 1, Bs, tid);
    }
  }

  // ---- epilogue: e = exp2(acc) (scale pre-folded); 3 wave-uniform paths ----
  float rsum[16];
  float csum[4];
  #pragma unroll
  for (int ii = 0; ii < 16; ++ii) rsum[ii] = 0.f;
  #pragma unroll
  for (int ii = 0; ii < 4; ++ii) csum[ii] = 0.f;

  if (dwave) {
    #pragma unroll
    for (int mi = 0; mi < 4; ++mi)
      #pragma unroll
      for (int ni = 0; ni < 4; ++ni) {
        int colloc = ni * 16 + c;
        #pragma unroll
        for (int r = 0; r < 4; ++r) {
          int rowloc = mi * 16 + g * 4 + r;
          float e = __builtin_amdgcn_exp2f(acc[mi][ni][r]);
          if (rowloc == colloc) e = 0.f;
          rsum[mi * 4 + r] += e;
        }
      }
  } else if (dblk) {
    #pragma unroll
    for (int mi = 0; mi < 4; ++mi)
      #pragma unroll
      for (int ni = 0; ni < 4; ++ni)
        #pragma unroll
        for (int r = 0; r < 4; ++r)
          rsum[mi * 4 + r] += __builtin_amdgcn_exp2f(acc[mi][ni][r]);
  } else {
    #pragma unroll
    for (int mi = 0; mi < 4; ++mi)
      #pragma unroll
      for (int ni = 0; ni < 4; ++ni)
        #pragma unroll
        for (int r = 0; r < 4; ++r) {
          float e = __builtin_amdgcn_exp2f(acc[mi][ni][r]);
          rsum[mi * 4 + r] += e;
          csum[ni]         += e;
        }
  }

  // row sums: reduce across the 16 column-lanes (lane bits 0-3)
  #pragma unroll
  for (int ii = 0; ii < 16; ++ii) {
    float v = rsum[ii];
    v += __shfl_xor(v, 1, 64);
    v += __shfl_xor(v, 2, 64);
    v += __shfl_xor(v, 4, 64);
    v += __shfl_xor(v, 8, 64);
    rsum[ii] = v;
  }
  if (c == 0) {
    #pragma unroll
    for (int mi = 0; mi < 4; ++mi)
      #pragma unroll
      for (int r = 0; r < 4; ++r)
        redR[wr * 64 + mi * 16 + g * 4 + r][wc] = rsum[mi * 4 + r];
  }
  if (!dblk) {
    // col sums: reduce across the 4 row-groups g (lane bits 4-5)
    #pragma unroll
    for (int ii = 0; ii < 4; ++ii) {
      float v = csum[ii];
      v += __shfl_xor(v, 16, 64);
      v += __shfl_xor(v, 32, 64);
      csum[ii] = v;
    }
    if (g == 0) {
      #pragma unroll
      for (int ni = 0; ni < 4; ++ni)
        redC[wc * 64 + ni * 16 + c][wr] = csum[ni];
    }
  }
  __syncthreads();
  if (tid < 128) {
    partial[(size_t)cb * twoN + rb * 128 + tid] =
        redR[tid][0] + redR[tid][1];
    if (rb != cb)
      partial[(size_t)rb * twoN + cb * 128 + tid] =
          redC[tid][0] + redC[tid][1];
  }
}

// ---- Kernel C: per-256-row sums of log(denom), pos; last block finishes ----
__global__ __launch_bounds__(256) void reduce_kernel(
    const float* __restrict__ partial, const float* __restrict__ pos,
    float* __restrict__ bsum, float* __restrict__ out, int* __restrict__ sync,
    int twoN, int N, int nsplit) {
  int row = blockIdx.x * 256 + threadIdx.x;
  int wid = threadIdx.x >> 6, lane = threadIdx.x & 63;
  float denom = 0.f;
  for (int s = 0; s < nsplit; ++s) denom += partial[(size_t)s * twoN + row];
  float ld = logf(denom);
  float p  = (row < N) ? pos[row] : 0.f;
  #pragma unroll
  for (int m = 1; m < 64; m <<= 1) {
    ld += __shfl_xor(ld, m, 64);
    p  += __shfl_xor(p, m, 64);
  }
  __shared__ float sld[4], spo[4];
  __shared__ int lastf;
  if (lane == 0) { sld[wid] = ld; spo[wid] = p; }
  __syncthreads();
  if (threadIdx.x == 0) {
    bsum[blockIdx.x]             = sld[0] + sld[1] + sld[2] + sld[3];
    bsum[gridDim.x + blockIdx.x] = spo[0] + spo[1] + spo[2] + spo[3];
    __threadfence();
    lastf = (atomicAdd(sync, 1) == (int)gridDim.x - 1);
  }
  __syncthreads();
  if (lastf && threadIdx.x < 64) {
    __threadfence();   // acquire other blocks' bsum
    int t = threadIdx.x;
    int nb = gridDim.x;
    float l2 = (t < nb) ? bsum[t] : 0.f;
    float p2 = (t < nb) ? bsum[nb + t] : 0.f;
    #pragma unroll
    for (int m = 1; m < 64; m <<= 1) {
      l2 += __shfl_xor(l2, m, 64);
      p2 += __shfl_xor(p2, m, 64);
    }
    if (t == 0) out[0] = l2 / (float)twoN - 2.f * (p2 / (float)N);
  }
}

extern "C" void kernel_launch(void* const* d_in, const int* in_sizes, int n_in,
                              void* d_out, int out_size, void* d_ws,
                              size_t ws_size, hipStream_t stream) {
  const float* z1 = (const float*)d_in[0];
  const float* z2 = (const float*)d_in[1];
  int N = in_sizes[0] / D;   // 4096
  int twoN = 2 * N;          // 8192
  int nrb = twoN / 128;      // 64 (= nsplit)

  // workspace layout
  unsigned char* fnq = (unsigned char*)d_ws;                     // 2 MB fp8
  float* partial = (float*)((char*)d_ws + (size_t)twoN * D);     // 2 MB
  float* pos     = (float*)((char*)partial + (size_t)nrb * twoN * 4);
  float* bsum    = (float*)((char*)pos + (size_t)N * 4);         // 64 floats
  int*   sync    = (int*)((char*)bsum + 256 * 4);

  normpos_kernel<<<N / 4, 256, 0, stream>>>(z1, z2, fnq, pos, sync, N);
  int ntri = nrb * (nrb + 1) / 2;  // 2080 upper-triangle blocks
  denom_kernel<<<ntri, 256, 0, stream>>>(fnq, partial, twoN);
  int nblk = twoN / 256;  // 32
  reduce_kernel<<<nblk, 256, 0, stream>>>(partial, pos, bsum, (float*)d_out,
                                          sync, twoN, N, nrb);
}

// Round 26
// 51.678 us; speedup vs baseline: 2.2706x; 1.0198x over previous
//
#include <hip/hip_runtime.h>
#include <hip/hip_fp8.h>

#define D 256
#define SCALE 1.69864354f   // sqrt((1/T)*log2e), T=0.5: acc=2.8854*cos -> exp2(acc)=exp(sim/T)
#define EPS 1e-8f
#define SCALE1 0x7F7F7F7F   // e8m0 127 = 2^0 = 1.0 in all four scale bytes

typedef __attribute__((ext_vector_type(4))) float f32x4;
typedef __attribute__((ext_vector_type(4))) int   i32x4;
typedef __attribute__((ext_vector_type(8))) int   i32x8;

// ------ Kernel A: row-normalize [z1;z2] -> fp8 fn (pre-scaled), fused pos ---
// Also zeroes the reduce sync counter (runs before reduce in stream order).
__global__ __launch_bounds__(256) void normpos_kernel(
    const float* __restrict__ z1, const float* __restrict__ z2,
    unsigned char* __restrict__ fnq, float* __restrict__ pos,
    int* __restrict__ sync, int N) {
  if (blockIdx.x == 0 && threadIdx.x == 0) *sync = 0;
  int wid  = threadIdx.x >> 6;
  int lane = threadIdx.x & 63;
  int row  = blockIdx.x * 4 + wid;
  f32x4 a = *(const f32x4*)(z1 + (size_t)row * D + lane * 4);
  f32x4 b = *(const f32x4*)(z2 + (size_t)row * D + lane * 4);
  float s1  = a.x * a.x + a.y * a.y + a.z * a.z + a.w * a.w;
  float s2  = b.x * b.x + b.y * b.y + b.z * b.z + b.w * b.w;
  float dot = a.x * b.x + a.y * b.y + a.z * b.z + a.w * b.w;
  #pragma unroll
  for (int m = 1; m < 64; m <<= 1) {
    s1  += __shfl_xor(s1, m, 64);
    s2  += __shfl_xor(s2, m, 64);
    dot += __shfl_xor(dot, m, 64);
  }
  float inv1 = 1.0f / fmaxf(sqrtf(s1), EPS);
  float inv2 = 1.0f / fmaxf(sqrtf(s2), EPS);
  float q1 = inv1 * SCALE, q2 = inv2 * SCALE;
  unsigned int w1 = 0, w2 = 0;
  #pragma unroll
  for (int j = 0; j < 4; ++j) {
    w1 |= (unsigned int)__hip_cvt_float_to_fp8(a[j] * q1, __HIP_SATFINITE,
                                               __HIP_E4M3) << (8 * j);
    w2 |= (unsigned int)__hip_cvt_float_to_fp8(b[j] * q2, __HIP_SATFINITE,
                                               __HIP_E4M3) << (8 * j);
  }
  *(unsigned int*)(fnq + (size_t)row * D + lane * 4)       = w1;
  *(unsigned int*)(fnq + (size_t)(N + row) * D + lane * 4) = w2;
  if (lane == 0) pos[row] = dot * inv1 * inv2;
}

// -------- Kernel B: denom partials, MX-fp8 symmetric triangle GEMM ---------
// R13/R25 skeleton (52.8us proven): 128x128 tile, 4 waves, single-buffered,
// BK=128, launch_bounds(256,4), 34 KB LDS -> 4 blocks/CU, triangle rb<=cb,
// rowsum -> partial[cb][rb-rows], colsum -> partial[rb][cb-rows] (off-diag),
// chunk swizzle (inverse-swizzled GLOBAL source + swizzled ds_read).
// R26 change: mfma_scale_f32_16x16x128_f8f6f4 (MX path, 2x fp8 rate), scales
// fixed at 1.0 (e8m0=127). One MFMA per 16x16 tile per kk (32/wave vs 64);
// each lane reads its 32B k-slice as two swizzled ds_read_b128 (chunks
// 2g,2g+1). k-permutation within the slice cancels between A and B (same
// addressing, dot is k-perm-invariant); C/D layout shape-determined
// (m121-m128); scale-encoding errors fail loudly.

__device__ __forceinline__ void stage_tile(const unsigned char* __restrict__ row0,
                                           int kk, unsigned char* lds, int tid) {
  // 128 rows x 128 k fp8 (16 KB) = 1024 chunks of 16B; 4 iters x 256 thr.
  #pragma unroll
  for (int it = 0; it < 4; ++it) {
    int s = it * 256 + tid;        // chunk slot; per-wave base + lane*16B ✓
    int r = s >> 3;                // row in tile
    int p = s & 7;                 // chunk-in-row (LDS position)
    const unsigned char* src =
        row0 + (size_t)r * D + kk * 128 + ((p ^ (r & 7)) << 4);
    __builtin_amdgcn_global_load_lds(
        (const __attribute__((address_space(1))) void*)src,
        (__attribute__((address_space(3))) void*)(lds + s * 16), 16, 0, 0);
  }
}

__global__ __launch_bounds__(256, 4) void denom_kernel(
    const unsigned char* __restrict__ fnq, float* __restrict__ partial,
    int twoN) {
  __shared__ unsigned char As[128 * 128];   // 16 KB
  __shared__ unsigned char Bs[128 * 128];   // 16 KB
  __shared__ float redR[128][2];            // 1 KB
  __shared__ float redC[128][2];            // 1 KB

  int tid  = threadIdx.x;
  int wid  = tid >> 6;
  int lane = tid & 63;
  int c = lane & 15;            // frag row/col within 16-tile
  int g = lane >> 4;            // k-group (in) / row-group (out)
  int wr = wid >> 1, wc = wid & 1;

  // decode lower-triangle linear index -> (rb<=cb)
  int bid = blockIdx.x;
  int i = (int)((sqrtf(8.f * (float)bid + 1.f) - 1.f) * 0.5f);
  while ((i + 1) * (i + 2) / 2 <= bid) ++i;
  while (i * (i + 1) / 2 > bid) --i;
  int rb = bid - i * (i + 1) / 2;   // row block  (rb <= cb)
  int cb = i;                       // col block
  const unsigned char* Arow0 = fnq + (size_t)rb * 128 * D;
  const unsigned char* Brow0 = fnq + (size_t)cb * 128 * D;

  bool dblk  = (rb == cb);
  bool dwave = dblk && (wr == wc);

  f32x4 acc[4][4] = {};

  stage_tile(Arow0, 0, As, tid);
  stage_tile(Brow0, 0, Bs, tid);

  #pragma unroll
  for (int kk = 0; kk < 2; ++kk) {
    __syncthreads();   // stage complete (vmcnt drained before barrier)
    i32x8 a[4], b[4];
    #pragma unroll
    for (int mi = 0; mi < 4; ++mi) {
      int ar = wr * 64 + mi * 16 + c;
      i32x4 lo = *(const i32x4*)(As + ar * 128 +
                                 ((((g << 1))     ^ (ar & 7)) << 4));
      i32x4 hi = *(const i32x4*)(As + ar * 128 +
                                 ((((g << 1) | 1) ^ (ar & 7)) << 4));
      a[mi][0] = lo[0]; a[mi][1] = lo[1]; a[mi][2] = lo[2]; a[mi][3] = lo[3];
      a[mi][4] = hi[0]; a[mi][5] = hi[1]; a[mi][6] = hi[2]; a[mi][7] = hi[3];
    }
    #pragma unroll
    for (int ni = 0; ni < 4; ++ni) {
      int bc = wc * 64 + ni * 16 + c;
      i32x4 lo = *(const i32x4*)(Bs + bc * 128 +
                                 ((((g << 1))     ^ (bc & 7)) << 4));
      i32x4 hi = *(const i32x4*)(Bs + bc * 128 +
                                 ((((g << 1) | 1) ^ (bc & 7)) << 4));
      b[ni][0] = lo[0]; b[ni][1] = lo[1]; b[ni][2] = lo[2]; b[ni][3] = lo[3];
      b[ni][4] = hi[0]; b[ni][5] = hi[1]; b[ni][6] = hi[2]; b[ni][7] = hi[3];
    }
    #pragma unroll
    for (int mi = 0; mi < 4; ++mi)
      #pragma unroll
      for (int ni = 0; ni < 4; ++ni)
        acc[mi][ni] = __builtin_amdgcn_mfma_scale_f32_16x16x128_f8f6f4(
            a[mi], b[ni], acc[mi][ni], 0 /*A fmt fp8*/, 0 /*B fmt fp8*/,
            0, SCALE1, 0, SCALE1);
    if (kk == 0) {
      __syncthreads();               // protect LDS before restage
      stage_tile(Arow0, 1, As, tid);
      stage_tile(Brow0, 1, Bs, tid);
    }
  }

  // ---- epilogue: e = exp2(acc) (scale pre-folded); 3 wave-uniform paths ----
  float rsum[16];
  float csum[4];
  #pragma unroll
  for (int ii = 0; ii < 16; ++ii) rsum[ii] = 0.f;
  #pragma unroll
  for (int ii = 0; ii < 4; ++ii) csum[ii] = 0.f;

  if (dwave) {
    #pragma unroll
    for (int mi = 0; mi < 4; ++mi)
      #pragma unroll
      for (int ni = 0; ni < 4; ++ni) {
        int colloc = ni * 16 + c;
        #pragma unroll
        for (int r = 0; r < 4; ++r) {
          int rowloc = mi * 16 + g * 4 + r;
          float e = __builtin_amdgcn_exp2f(acc[mi][ni][r]);
          if (rowloc == colloc) e = 0.f;
          rsum[mi * 4 + r] += e;
        }
      }
  } else if (dblk) {
    #pragma unroll
    for (int mi = 0; mi < 4; ++mi)
      #pragma unroll
      for (int ni = 0; ni < 4; ++ni)
        #pragma unroll
        for (int r = 0; r < 4; ++r)
          rsum[mi * 4 + r] += __builtin_amdgcn_exp2f(acc[mi][ni][r]);
  } else {
    #pragma unroll
    for (int mi = 0; mi < 4; ++mi)
      #pragma unroll
      for (int ni = 0; ni < 4; ++ni)
        #pragma unroll
        for (int r = 0; r < 4; ++r) {
          float e = __builtin_amdgcn_exp2f(acc[mi][ni][r]);
          rsum[mi * 4 + r] += e;
          csum[ni]         += e;
        }
  }

  // row sums: reduce across the 16 column-lanes (lane bits 0-3)
  #pragma unroll
  for (int ii = 0; ii < 16; ++ii) {
    float v = rsum[ii];
    v += __shfl_xor(v, 1, 64);
    v += __shfl_xor(v, 2, 64);
    v += __shfl_xor(v, 4, 64);
    v += __shfl_xor(v, 8, 64);
    rsum[ii] = v;
  }
  if (c == 0) {
    #pragma unroll
    for (int mi = 0; mi < 4; ++mi)
      #pragma unroll
      for (int r = 0; r < 4; ++r)
        redR[wr * 64 + mi * 16 + g * 4 + r][wc] = rsum[mi * 4 + r];
  }
  if (!dblk) {
    // col sums: reduce across the 4 row-groups g (lane bits 4-5)
    #pragma unroll
    for (int ii = 0; ii < 4; ++ii) {
      float v = csum[ii];
      v += __shfl_xor(v, 16, 64);
      v += __shfl_xor(v, 32, 64);
      csum[ii] = v;
    }
    if (g == 0) {
      #pragma unroll
      for (int ni = 0; ni < 4; ++ni)
        redC[wc * 64 + ni * 16 + c][wr] = csum[ni];
    }
  }
  __syncthreads();
  if (tid < 128) {
    partial[(size_t)cb * twoN + rb * 128 + tid] =
        redR[tid][0] + redR[tid][1];
    if (rb != cb)
      partial[(size_t)rb * twoN + cb * 128 + tid] =
          redC[tid][0] + redC[tid][1];
  }
}

// ---- Kernel C: per-256-row sums of log(denom), pos; last block finishes ----
__global__ __launch_bounds__(256) void reduce_kernel(
    const float* __restrict__ partial, const float* __restrict__ pos,
    float* __restrict__ bsum, float* __restrict__ out, int* __restrict__ sync,
    int twoN, int N, int nsplit) {
  int row = blockIdx.x * 256 + threadIdx.x;
  int wid = threadIdx.x >> 6, lane = threadIdx.x & 63;
  float denom = 0.f;
  for (int s = 0; s < nsplit; ++s) denom += partial[(size_t)s * twoN + row];
  float ld = logf(denom);
  float p  = (row < N) ? pos[row] : 0.f;
  #pragma unroll
  for (int m = 1; m < 64; m <<= 1) {
    ld += __shfl_xor(ld, m, 64);
    p  += __shfl_xor(p, m, 64);
  }
  __shared__ float sld[4], spo[4];
  __shared__ int lastf;
  if (lane == 0) { sld[wid] = ld; spo[wid] = p; }
  __syncthreads();
  if (threadIdx.x == 0) {
    bsum[blockIdx.x]             = sld[0] + sld[1] + sld[2] + sld[3];
    bsum[gridDim.x + blockIdx.x] = spo[0] + spo[1] + spo[2] + spo[3];
    __threadfence();
    lastf = (atomicAdd(sync, 1) == (int)gridDim.x - 1);
  }
  __syncthreads();
  if (lastf && threadIdx.x < 64) {
    __threadfence();   // acquire other blocks' bsum
    int t = threadIdx.x;
    int nb = gridDim.x;
    float l2 = (t < nb) ? bsum[t] : 0.f;
    float p2 = (t < nb) ? bsum[nb + t] : 0.f;
    #pragma unroll
    for (int m = 1; m < 64; m <<= 1) {
      l2 += __shfl_xor(l2, m, 64);
      p2 += __shfl_xor(p2, m, 64);
    }
    if (t == 0) out[0] = l2 / (float)twoN - 2.f * (p2 / (float)N);
  }
}

extern "C" void kernel_launch(void* const* d_in, const int* in_sizes, int n_in,
                              void* d_out, int out_size, void* d_ws,
                              size_t ws_size, hipStream_t stream) {
  const float* z1 = (const float*)d_in[0];
  const float* z2 = (const float*)d_in[1];
  int N = in_sizes[0] / D;   // 4096
  int twoN = 2 * N;          // 8192
  int nrb = twoN / 128;      // 64 (= nsplit)

  // workspace layout
  unsigned char* fnq = (unsigned char*)d_ws;                     // 2 MB fp8
  float* partial = (float*)((char*)d_ws + (size_t)twoN * D);     // 2 MB
  float* pos     = (float*)((char*)partial + (size_t)nrb * twoN * 4);
  float* bsum    = (float*)((char*)pos + (size_t)N * 4);         // 64 floats
  int*   sync    = (int*)((char*)bsum + 256 * 4);

  normpos_kernel<<<N / 4, 256, 0, stream>>>(z1, z2, fnq, pos, sync, N);
  int ntri = nrb * (nrb + 1) / 2;  // 2080 upper-triangle blocks
  denom_kernel<<<ntri, 256, 0, stream>>>(fnq, partial, twoN);
  int nblk = twoN / 256;  // 32
  reduce_kernel<<<nblk, 256, 0, stream>>>(partial, pos, bsum, (float*)d_out,
                                          sync, twoN, N, nrb);
}